// Round 6
// baseline (233.024 us; speedup 1.0000x reference)
//
#include <hip/hip_runtime.h>

#define B_    8
#define LV_   4096
#define D_    256
#define N_    2048
#define P_    32
#define WROWS_ 64                 // rows per LDS window (64 KB tile)
#define NWIN_  (B_ * (LV_ / WROWS_))   // 512 (batch,window) keys
#define NBINS_ (N_ * P_)          // 65536
#define CPB_   16                 // bins per block (chunk)

typedef float v4f __attribute__((ext_vector_type(4)));

__device__ __forceinline__ float lane_bcast_f(float v, int l) {
    return __int_as_float(__builtin_amdgcn_readlane(__float_as_int(v), l));
}

// First row touched by bin (n,p) — same clamping as the main math. Used only
// for window ASSIGNMENT (performance); per-row in/out-of-window checks in the
// main kernel guarantee correctness regardless.
__device__ __forceinline__ int bin_r_first(const float* __restrict__ boxes, int n, int p) {
    const float y1 = boxes[2 * n], y2 = boxes[2 * n + 1];
    const float bin_h = (y2 - y1) * (1.0f / (float)P_);
    const int gh = (int)ceilf(bin_h);
    if (gh < 1) return 0;
    const float sub  = bin_h / (float)gh;
    const float boff = (y1 - 0.5f) + (float)p * bin_h;
    const float a    = fmaf(0.5f, sub, boff);
    int r = (int)floorf(a);
    if (r < 0) r = 0;
    if (r > LV_ - 1) r = LV_ - 1;
    return r;
}

// Pre-pass (fast path): counting-sort all 65536 bins by (batch, window) into
// binlist. Single block, LDS counters, two strided passes + serial prefix.
__global__ __launch_bounds__(1024) void build_binlist_kernel(
    const float* __restrict__ boxes, const int* __restrict__ batch_idx,
    int* __restrict__ binlist)
{
    __shared__ int cnt[NWIN_], cur[NWIN_];
    const int tid = threadIdx.x;
    for (int i = tid; i < NWIN_; i += 1024) cnt[i] = 0;
    __syncthreads();
    for (int idx = tid; idx < NBINS_; idx += 1024) {
        const int n = idx >> 5, p = idx & 31;
        const int key = (batch_idx[n] << 6) | (bin_r_first(boxes, n, p) >> 6);
        atomicAdd(&cnt[key], 1);
    }
    __syncthreads();
    if (tid == 0) { int s = 0; for (int k = 0; k < NWIN_; ++k) { cur[k] = s; s += cnt[k]; } }
    __syncthreads();
    for (int idx = tid; idx < NBINS_; idx += 1024) {
        const int n = idx >> 5, p = idx & 31;
        const int key = (batch_idx[n] << 6) | (bin_r_first(boxes, n, p) >> 6);
        binlist[atomicAdd(&cur[key], 1)] = idx;
    }
}

// ---------------- fallback path (R5 kernels, used when ws too small) --------
__global__ __launch_bounds__(256) void build_order_kernel(
    const int* __restrict__ batch_idx, int* __restrict__ order)
{
    __shared__ int cnt[B_], cur[B_];
    const int tid = threadIdx.x;
    if (tid < B_) cnt[tid] = 0;
    __syncthreads();
    for (int n = tid; n < N_; n += 256) atomicAdd(&cnt[batch_idx[n]], 1);
    __syncthreads();
    if (tid == 0) { int s = 0; for (int b = 0; b < B_; ++b) { cur[b] = s; s += cnt[b]; } }
    __syncthreads();
    for (int n = tid; n < N_; n += 256)
        order[atomicAdd(&cur[batch_idx[n]], 1)] = n;
}

__global__ __launch_bounds__(256) void roi_rows_kernel(
    const float* __restrict__ feat, const float* __restrict__ boxes,
    const int* __restrict__ batch_idx, const int* __restrict__ order,
    float* __restrict__ out)
{
    const int nwg = (N_ * P_) / 4;
    const int cpx = nwg >> 3;
    const int bid = blockIdx.x;
    const int swz = (bid & 7) * cpx + (bid >> 3);
    const int slot = (swz << 2) + (threadIdx.x >> 6);
    const int n    = __builtin_amdgcn_readfirstlane(order[slot >> 5]);
    const int p    = slot & (P_ - 1);
    const int lane = threadIdx.x & 63;
    const int bi   = __builtin_amdgcn_readfirstlane(batch_idx[n]);
    const float y1 = boxes[2 * n], y2 = boxes[2 * n + 1];
    const float bin_h = (y2 - y1) * (1.0f / (float)P_);
    const int gh = (int)ceilf(bin_h);
    const v4f* prow = (const v4f*)feat + (long)bi * (LV_ * (D_ / 4));
    v4f acc0 = {0.f,0.f,0.f,0.f}, acc1 = {0.f,0.f,0.f,0.f};
    if (gh >= 1) {
        const float cntf = (float)gh, sub = bin_h / cntf, inv_sub = 1.0f / sub;
        const float halfsub = 0.5f * sub;
        const float boff = (y1 - 0.5f) + (float)p * bin_h;
        const float a = fmaf(0.5f, sub, boff), ylast = fmaf(cntf - 0.5f, sub, boff);
        int r_first = (int)floorf(a);
        if (r_first < 0) r_first = 0; if (r_first > LV_-1) r_first = LV_-1;
        int r_last = (int)floorf(ylast) + 1;
        if (r_last > LV_-1) r_last = LV_-1; if (r_last < r_first) r_last = r_first;
        const int r0 = __builtin_amdgcn_readfirstlane(r_first);
        const int rl = __builtin_amdgcn_readfirstlane(r_last);
        const float lanef = (float)lane;
        for (int base = r0; base <= rl; base += 64) {
            int kmax = rl - base; if (kmax > 63) kmax = 63;
            const int r = base + lane;
            const float d0 = ((float)base + lanef) - a;
            const float dm = d0 - 1.0f, dp = d0 + 1.0f;
            const float nm = fminf(fmaxf(ceilf(dm * inv_sub), 0.0f), cntf);
            const float n0 = fminf(fmaxf(ceilf(d0 * inv_sub), 0.0f), cntf);
            const float np = fminf(fmaxf(ceilf(dp * inv_sub), 0.0f), cntf);
            float Pm = fmaf(nm, dm, -halfsub * fmaf(nm, nm, -nm));
            float P0 = fmaf(n0, d0, -halfsub * fmaf(n0, n0, -n0));
            float Pp = fmaf(np, dp, -halfsub * fmaf(np, np, -np));
            if (r == 0)       Pm = P0;
            if (r == LV_ - 1) Pp = P0 + cntf;
            const float Wl = (Pm + Pp) - 2.0f * P0;
            const v4f* pS = prow + (long)base * (D_ / 4);
            int k = 0;
            for (; k + 4 <= kmax + 1; k += 4) {
                v4f v0 = pS[lane], v1 = pS[lane+64], v2 = pS[lane+128], v3 = pS[lane+192];
                acc0 += v0 * lane_bcast_f(Wl, k);   acc1 += v1 * lane_bcast_f(Wl, k+1);
                acc0 += v2 * lane_bcast_f(Wl, k+2); acc1 += v3 * lane_bcast_f(Wl, k+3);
                pS += 4 * (D_ / 4);
            }
            for (; k <= kmax; ++k) { v4f v = pS[lane]; acc0 += v * lane_bcast_f(Wl, k); pS += (D_ / 4); }
        }
    }
    const float inv_c = 1.0f / (float)(gh > 1 ? gh : 1);
    v4f res = (acc0 + acc1) * inv_c;
    v4f* op = (v4f*)out + ((long)n * P_ + p) * (D_ / 4) + lane;
    __builtin_nontemporal_store(res, op);
}
// ---------------------------------------------------------------------------

// Main kernel (fast path): block = 16 sorted bins + one 64-row LDS window.
// R6 rationale: R2/R4/R5 all landed at exactly 124us despite different VALU/
// occupancy/pipelining -> per-CU global conduit (~16cy per 1KB wave-row) is
// the wall. Rows are reused ~87x; move the bulk of row reads to the LDS pipe
// (~2x B/cy). Bins sorted by (batch,window) share a staged window; the
// overhang (~1/3 of rows, next window over -> L2-hot) stays on the global
// path. Per-bin math identical to R5 -> bitwise-same weights, same absmax.
__global__ __launch_bounds__(512) void roi_win_kernel(
    const float* __restrict__ feat, const float* __restrict__ boxes,
    const int* __restrict__ batch_idx, const int* __restrict__ binlist,
    float* __restrict__ out)
{
    __shared__ v4f tile[WROWS_ * 64];                  // 64 KB -> 2 blocks/CU
    const int nblk = NBINS_ / CPB_;                    // 4096
    const int bid  = blockIdx.x;
    const int blk  = (bid & 7) * (nblk >> 3) + (bid >> 3);  // bijective XCD swizzle
    const int tid  = threadIdx.x;
    const int lane = tid & 63;
    const int wv   = tid >> 6;                         // wave 0..7

    // window identity from the chunk's first bin (list sorted by (b,w))
    const int idx0 = binlist[blk * CPB_];
    const int wb   = __builtin_amdgcn_readfirstlane(batch_idx[idx0 >> 5]);
    const int wlo  = __builtin_amdgcn_readfirstlane(
                         (bin_r_first(boxes, idx0 >> 5, idx0 & 31) >> 6) << 6);

    // ---- stage window: 8 waves x 8 rows each, reg-staged (8 loads then 8 writes)
    {
        const v4f* src = (const v4f*)feat + ((long)wb * LV_ + wlo) * (D_ / 4) + lane;
        const int r0 = wv * 8;
        v4f t0 = src[(r0+0)*64], t1 = src[(r0+1)*64], t2 = src[(r0+2)*64], t3 = src[(r0+3)*64];
        v4f t4 = src[(r0+4)*64], t5 = src[(r0+5)*64], t6 = src[(r0+6)*64], t7 = src[(r0+7)*64];
        v4f* dst = tile + r0 * 64 + lane;
        dst[0]   = t0; dst[64]  = t1; dst[128] = t2; dst[192] = t3;
        dst[256] = t4; dst[320] = t5; dst[384] = t6; dst[448] = t7;
    }
    __syncthreads();

    // ---- each wave: 2 bins, independent ----
    for (int i = wv; i < CPB_; i += 8) {
        const int idx = __builtin_amdgcn_readfirstlane(binlist[blk * CPB_ + i]);
        const int n = idx >> 5, p = idx & 31;
        const int bi = __builtin_amdgcn_readfirstlane(batch_idx[n]);

        const float y1 = boxes[2 * n], y2 = boxes[2 * n + 1];
        const float bin_h = (y2 - y1) * (1.0f / (float)P_);
        const int gh = (int)ceilf(bin_h);

        const v4f* prow = (const v4f*)feat + (long)bi * (LV_ * (D_ / 4));
        v4f acc0 = {0.f,0.f,0.f,0.f}, acc1 = {0.f,0.f,0.f,0.f};

        if (gh >= 1) {
            const float cntf = (float)gh, sub = bin_h / cntf, inv_sub = 1.0f / sub;
            const float halfsub = 0.5f * sub;
            const float boff = (y1 - 0.5f) + (float)p * bin_h;
            const float a = fmaf(0.5f, sub, boff), ylast = fmaf(cntf - 0.5f, sub, boff);

            int r_first = (int)floorf(a);
            if (r_first < 0) r_first = 0; if (r_first > LV_-1) r_first = LV_-1;
            int r_last = (int)floorf(ylast) + 1;
            if (r_last > LV_-1) r_last = LV_-1; if (r_last < r_first) r_last = r_first;
            const int r0 = __builtin_amdgcn_readfirstlane(r_first);
            const int rl = __builtin_amdgcn_readfirstlane(r_last);
            const float lanef = (float)lane;

            for (int gbase = r0; gbase <= rl; gbase += 64) {
                int kmax = rl - gbase; if (kmax > 63) kmax = 63;

                // lane-parallel closed-form weights (identical to R5)
                const int   r  = gbase + lane;
                const float d0 = ((float)gbase + lanef) - a;
                const float dm = d0 - 1.0f, dp = d0 + 1.0f;
                const float nm = fminf(fmaxf(ceilf(dm * inv_sub), 0.0f), cntf);
                const float n0 = fminf(fmaxf(ceilf(d0 * inv_sub), 0.0f), cntf);
                const float np = fminf(fmaxf(ceilf(dp * inv_sub), 0.0f), cntf);
                float Pm = fmaf(nm, dm, -halfsub * fmaf(nm, nm, -nm));
                float P0 = fmaf(n0, d0, -halfsub * fmaf(n0, n0, -n0));
                float Pp = fmaf(np, dp, -halfsub * fmaf(np, np, -np));
                if (r == 0)       Pm = P0;
                if (r == LV_ - 1) Pp = P0 + cntf;
                const float Wl = (Pm + Pp) - 2.0f * P0;

                // split k-range into [0,lo) global | [lo,hi) LDS | [hi,t) global
                const int t = kmax + 1;
                int lo, hi;
                if (bi == wb) {
                    lo = wlo - gbase;          lo = lo < 0 ? 0 : (lo > t ? t : lo);
                    hi = wlo + WROWS_ - gbase; hi = hi < lo ? lo : (hi > t ? t : hi);
                } else { lo = t; hi = t; }

#define GSEG(KS, KE) do {                                                        \
    int k = (KS);                                                                \
    const v4f* pS = prow + (long)(gbase + k) * (D_ / 4);                         \
    for (; k + 4 <= (KE); k += 4) {                                              \
        v4f v0 = pS[lane], v1 = pS[lane+64], v2 = pS[lane+128], v3 = pS[lane+192];\
        acc0 += v0 * lane_bcast_f(Wl, k);   acc1 += v1 * lane_bcast_f(Wl, k+1);  \
        acc0 += v2 * lane_bcast_f(Wl, k+2); acc1 += v3 * lane_bcast_f(Wl, k+3);  \
        pS += 4 * (D_ / 4); }                                                    \
    for (; k < (KE); ++k) { v4f v = pS[lane]; acc0 += v * lane_bcast_f(Wl, k); pS += (D_ / 4); } \
} while (0)

                GSEG(0, lo);                               // prefix (usually empty)
                {                                          // LDS mid-segment
                    int k = lo;
                    const v4f* tp = tile + (gbase + lo - wlo) * 64 + lane;
                    for (; k + 4 <= hi; k += 4) {
                        v4f t0 = tp[0], t1 = tp[64], t2 = tp[128], t3 = tp[192];
                        acc0 += t0 * lane_bcast_f(Wl, k);   acc1 += t1 * lane_bcast_f(Wl, k+1);
                        acc0 += t2 * lane_bcast_f(Wl, k+2); acc1 += t3 * lane_bcast_f(Wl, k+3);
                        tp += 256;
                    }
                    for (; k < hi; ++k) { acc0 += tp[0] * lane_bcast_f(Wl, k); tp += 64; }
                }
                GSEG(hi, t);                               // suffix overhang
#undef GSEG
            }
        }

        const float inv_c = 1.0f / (float)(gh > 1 ? gh : 1);
        v4f res = (acc0 + acc1) * inv_c;
        v4f* op = (v4f*)out + ((long)n * P_ + p) * (D_ / 4) + lane;
        __builtin_nontemporal_store(res, op);
    }
}

extern "C" void kernel_launch(void* const* d_in, const int* in_sizes, int n_in,
                              void* d_out, int out_size, void* d_ws, size_t ws_size,
                              hipStream_t stream) {
    const float* feat      = (const float*)d_in[0];
    const float* boxes     = (const float*)d_in[1];
    const int*   batch_idx = (const int*)d_in[2];
    float*       out       = (float*)d_out;

    if (ws_size >= (size_t)NBINS_ * sizeof(int)) {
        int* binlist = (int*)d_ws;                       // 256 KB
        build_binlist_kernel<<<1, 1024, 0, stream>>>(boxes, batch_idx, binlist);
        roi_win_kernel<<<NBINS_ / CPB_, 512, 0, stream>>>(feat, boxes, batch_idx, binlist, out);
    } else {                                             // fallback: R5 path
        int* order = (int*)d_ws;                         // 8 KB
        build_order_kernel<<<1, 256, 0, stream>>>(batch_idx, order);
        roi_rows_kernel<<<(N_ * P_) / 4, 256, 0, stream>>>(feat, boxes, batch_idx, order, out);
    }
}

// Round 7
// 212.544 us; speedup vs baseline: 1.0964x; 1.0964x over previous
//
#include <hip/hip_runtime.h>

#define B_    8
#define LV_   4096
#define D_    256
#define N_    2048
#define P_    32
#define WROWS_ 64                      // rows per LDS window (64 KB tile)
#define NWIN_  (B_ * (LV_ / WROWS_))   // 512 (batch,window) keys
#define NBINS_ (N_ * P_)               // 65536
#define CPB_   32                      // bins per block

typedef float v4f __attribute__((ext_vector_type(4)));

__device__ __forceinline__ float lane_bcast_f(float v, int l) {
    return __int_as_float(__builtin_amdgcn_readlane(__float_as_int(v), l));
}

// First row touched by bin (n,p) — same clamping as the main math. Used only
// for window ASSIGNMENT (performance); per-row in/out-of-window interval
// clamps in the main kernel guarantee correctness regardless.
__device__ __forceinline__ int bin_r_first(const float* __restrict__ boxes, int n, int p) {
    const float y1 = boxes[2 * n], y2 = boxes[2 * n + 1];
    const float bin_h = (y2 - y1) * (1.0f / (float)P_);
    const int gh = (int)ceilf(bin_h);
    if (gh < 1) return 0;
    const float sub  = bin_h / (float)gh;
    const float boff = (y1 - 0.5f) + (float)p * bin_h;
    const float a    = fmaf(0.5f, sub, boff);
    int r = (int)floorf(a);
    if (r < 0) r = 0;
    if (r > LV_ - 1) r = LV_ - 1;
    return r;
}

__device__ __forceinline__ int bin_key(const float* __restrict__ boxes,
                                       const int* __restrict__ batch_idx, int idx) {
    const int n = idx >> 5, p = idx & 31;
    return (batch_idx[n] << 6) | (bin_r_first(boxes, n, p) >> 6);
}

// ---- R7 pre-pass: PARALLEL counting sort (R6's single-block version was ~50us)
__global__ __launch_bounds__(256) void count_bins_kernel(
    const float* __restrict__ boxes, const int* __restrict__ batch_idx,
    int* __restrict__ cnt)
{
    const int idx = blockIdx.x * 256 + threadIdx.x;
    atomicAdd(&cnt[bin_key(boxes, batch_idx, idx)], 1);
}

__global__ __launch_bounds__(NWIN_) void scan_kernel(int* __restrict__ cnt)
{
    __shared__ int s[NWIN_];
    const int t = threadIdx.x;
    s[t] = cnt[t];
    __syncthreads();
    for (int off = 1; off < NWIN_; off <<= 1) {            // Hillis-Steele inclusive
        const int v = (t >= off) ? s[t - off] : 0;
        __syncthreads();
        s[t] += v;
        __syncthreads();
    }
    cnt[t] = (t == 0) ? 0 : s[t - 1];                      // exclusive prefix
}

__global__ __launch_bounds__(256) void scatter_bins_kernel(
    const float* __restrict__ boxes, const int* __restrict__ batch_idx,
    int* __restrict__ cnt, int* __restrict__ binlist)
{
    const int idx = blockIdx.x * 256 + threadIdx.x;
    binlist[atomicAdd(&cnt[bin_key(boxes, batch_idx, idx)], 1)] = idx;
}

// ---------------- fallback path (R5 kernels, used when ws too small) --------
__global__ __launch_bounds__(256) void build_order_kernel(
    const int* __restrict__ batch_idx, int* __restrict__ order)
{
    __shared__ int cnt[B_], cur[B_];
    const int tid = threadIdx.x;
    if (tid < B_) cnt[tid] = 0;
    __syncthreads();
    for (int n = tid; n < N_; n += 256) atomicAdd(&cnt[batch_idx[n]], 1);
    __syncthreads();
    if (tid == 0) { int s = 0; for (int b = 0; b < B_; ++b) { cur[b] = s; s += cnt[b]; } }
    __syncthreads();
    for (int n = tid; n < N_; n += 256)
        order[atomicAdd(&cur[batch_idx[n]], 1)] = n;
}

__global__ __launch_bounds__(256) void roi_rows_kernel(
    const float* __restrict__ feat, const float* __restrict__ boxes,
    const int* __restrict__ batch_idx, const int* __restrict__ order,
    float* __restrict__ out)
{
    const int nwg = (N_ * P_) / 4;
    const int cpx = nwg >> 3;
    const int bid = blockIdx.x;
    const int swz = (bid & 7) * cpx + (bid >> 3);
    const int slot = (swz << 2) + (threadIdx.x >> 6);
    const int n    = __builtin_amdgcn_readfirstlane(order[slot >> 5]);
    const int p    = slot & (P_ - 1);
    const int lane = threadIdx.x & 63;
    const int bi   = __builtin_amdgcn_readfirstlane(batch_idx[n]);
    const float y1 = boxes[2 * n], y2 = boxes[2 * n + 1];
    const float bin_h = (y2 - y1) * (1.0f / (float)P_);
    const int gh = (int)ceilf(bin_h);
    const v4f* prow = (const v4f*)feat + (long)bi * (LV_ * (D_ / 4));
    v4f acc0 = {0.f,0.f,0.f,0.f}, acc1 = {0.f,0.f,0.f,0.f};
    if (gh >= 1) {
        const float cntf = (float)gh, sub = bin_h / cntf, inv_sub = 1.0f / sub;
        const float halfsub = 0.5f * sub;
        const float boff = (y1 - 0.5f) + (float)p * bin_h;
        const float a = fmaf(0.5f, sub, boff), ylast = fmaf(cntf - 0.5f, sub, boff);
        int r_first = (int)floorf(a);
        if (r_first < 0) r_first = 0; if (r_first > LV_-1) r_first = LV_-1;
        int r_last = (int)floorf(ylast) + 1;
        if (r_last > LV_-1) r_last = LV_-1; if (r_last < r_first) r_last = r_first;
        const int r0 = __builtin_amdgcn_readfirstlane(r_first);
        const int rl = __builtin_amdgcn_readfirstlane(r_last);
        const float lanef = (float)lane;
        for (int base = r0; base <= rl; base += 64) {
            int kmax = rl - base; if (kmax > 63) kmax = 63;
            const int r = base + lane;
            const float d0 = ((float)base + lanef) - a;
            const float dm = d0 - 1.0f, dp = d0 + 1.0f;
            const float nm = fminf(fmaxf(ceilf(dm * inv_sub), 0.0f), cntf);
            const float n0 = fminf(fmaxf(ceilf(d0 * inv_sub), 0.0f), cntf);
            const float np = fminf(fmaxf(ceilf(dp * inv_sub), 0.0f), cntf);
            float Pm = fmaf(nm, dm, -halfsub * fmaf(nm, nm, -nm));
            float P0 = fmaf(n0, d0, -halfsub * fmaf(n0, n0, -n0));
            float Pp = fmaf(np, dp, -halfsub * fmaf(np, np, -np));
            if (r == 0)       Pm = P0;
            if (r == LV_ - 1) Pp = P0 + cntf;
            const float Wl = (Pm + Pp) - 2.0f * P0;
            const v4f* pS = prow + (long)base * (D_ / 4);
            int k = 0;
            for (; k + 4 <= kmax + 1; k += 4) {
                v4f v0 = pS[lane], v1 = pS[lane+64], v2 = pS[lane+128], v3 = pS[lane+192];
                acc0 += v0 * lane_bcast_f(Wl, k);   acc1 += v1 * lane_bcast_f(Wl, k+1);
                acc0 += v2 * lane_bcast_f(Wl, k+2); acc1 += v3 * lane_bcast_f(Wl, k+3);
                pS += 4 * (D_ / 4);
            }
            for (; k <= kmax; ++k) { v4f v = pS[lane]; acc0 += v * lane_bcast_f(Wl, k); pS += (D_ / 4); }
        }
    }
    const float inv_c = 1.0f / (float)(gh > 1 ? gh : 1);
    v4f res = (acc0 + acc1) * inv_c;
    v4f* op = (v4f*)out + ((long)n * P_ + p) * (D_ / 4) + lane;
    __builtin_nontemporal_store(res, op);
}
// ---------------------------------------------------------------------------

// Main kernel: block = 32 sorted bins + one 64-row LDS window.
// R6 measured the window path at 112us (vs 124 global-only wall) but lost it
// to a ~50us serial pre-pass. R7: parallel pre-pass, CPB 16->32 (staging
// redundancy 256->128MB), and global_load_lds (16B) staging (no reg
// round-trip / vmcnt drain in the stage phase).
__global__ __launch_bounds__(512) void roi_win_kernel(
    const float* __restrict__ feat, const float* __restrict__ boxes,
    const int* __restrict__ batch_idx, const int* __restrict__ binlist,
    float* __restrict__ out)
{
    __shared__ v4f tile[WROWS_ * 64];                  // 64 KB -> 2 blocks/CU
    const int nblk = NBINS_ / CPB_;                    // 2048
    const int bid  = blockIdx.x;
    const int blk  = (bid & 7) * (nblk >> 3) + (bid >> 3);  // bijective XCD swizzle
    const int tid  = threadIdx.x;
    const int lane = tid & 63;
    const int wv   = tid >> 6;                         // wave 0..7

    // window identity from the chunk's first bin (list sorted by (b,w))
    const int idx0 = binlist[blk * CPB_];
    const int wb   = __builtin_amdgcn_readfirstlane(batch_idx[idx0 >> 5]);
    const int wlo  = __builtin_amdgcn_readfirstlane(
                         (bin_r_first(boxes, idx0 >> 5, idx0 & 31) >> 6) << 6);

    // ---- stage window: 8 waves x 8 rows, direct global->LDS (lane*16B layout)
    {
        const int r0 = wv * 8;
        const float* srow = feat + ((long)wb * LV_ + wlo + r0) * D_ + lane * 4;
        v4f* lrow = tile + r0 * 64;
#if __has_builtin(__builtin_amdgcn_global_load_lds)
        #pragma unroll
        for (int j = 0; j < 8; ++j) {
            __builtin_amdgcn_global_load_lds(
                (const __attribute__((address_space(1))) void*)(srow + j * D_),
                (__attribute__((address_space(3))) void*)(lrow + j * 64),
                16, 0, 0);
        }
#else
        const v4f* src = (const v4f*)feat + ((long)wb * LV_ + wlo + r0) * (D_ / 4) + lane;
        v4f t0 = src[0],   t1 = src[64],  t2 = src[128], t3 = src[192];
        v4f t4 = src[256], t5 = src[320], t6 = src[384], t7 = src[448];
        v4f* dst = lrow + lane;
        dst[0]   = t0; dst[64]  = t1; dst[128] = t2; dst[192] = t3;
        dst[256] = t4; dst[320] = t5; dst[384] = t6; dst[448] = t7;
#endif
    }
    __syncthreads();                                   // drains vmcnt+lgkmcnt

    // ---- each wave: 4 bins, independent ----
    for (int i = wv; i < CPB_; i += 8) {
        const int idx = __builtin_amdgcn_readfirstlane(binlist[blk * CPB_ + i]);
        const int n = idx >> 5, p = idx & 31;
        const int bi = __builtin_amdgcn_readfirstlane(batch_idx[n]);

        const float y1 = boxes[2 * n], y2 = boxes[2 * n + 1];
        const float bin_h = (y2 - y1) * (1.0f / (float)P_);
        const int gh = (int)ceilf(bin_h);

        const v4f* prow = (const v4f*)feat + (long)bi * (LV_ * (D_ / 4));
        v4f acc0 = {0.f,0.f,0.f,0.f}, acc1 = {0.f,0.f,0.f,0.f};

        if (gh >= 1) {
            const float cntf = (float)gh, sub = bin_h / cntf, inv_sub = 1.0f / sub;
            const float halfsub = 0.5f * sub;
            const float boff = (y1 - 0.5f) + (float)p * bin_h;
            const float a = fmaf(0.5f, sub, boff), ylast = fmaf(cntf - 0.5f, sub, boff);

            int r_first = (int)floorf(a);
            if (r_first < 0) r_first = 0; if (r_first > LV_-1) r_first = LV_-1;
            int r_last = (int)floorf(ylast) + 1;
            if (r_last > LV_-1) r_last = LV_-1; if (r_last < r_first) r_last = r_first;
            const int r0 = __builtin_amdgcn_readfirstlane(r_first);
            const int rl = __builtin_amdgcn_readfirstlane(r_last);
            const float lanef = (float)lane;

            for (int gbase = r0; gbase <= rl; gbase += 64) {
                int kmax = rl - gbase; if (kmax > 63) kmax = 63;

                // lane-parallel closed-form weights (identical to R5)
                const int   r  = gbase + lane;
                const float d0 = ((float)gbase + lanef) - a;
                const float dm = d0 - 1.0f, dp = d0 + 1.0f;
                const float nm = fminf(fmaxf(ceilf(dm * inv_sub), 0.0f), cntf);
                const float n0 = fminf(fmaxf(ceilf(d0 * inv_sub), 0.0f), cntf);
                const float np = fminf(fmaxf(ceilf(dp * inv_sub), 0.0f), cntf);
                float Pm = fmaf(nm, dm, -halfsub * fmaf(nm, nm, -nm));
                float P0 = fmaf(n0, d0, -halfsub * fmaf(n0, n0, -n0));
                float Pp = fmaf(np, dp, -halfsub * fmaf(np, np, -np));
                if (r == 0)       Pm = P0;
                if (r == LV_ - 1) Pp = P0 + cntf;
                const float Wl = (Pm + Pp) - 2.0f * P0;

                // split k-range into [0,lo) global | [lo,hi) LDS | [hi,t) global
                const int t = kmax + 1;
                int lo, hi;
                if (bi == wb) {
                    lo = wlo - gbase;          lo = lo < 0 ? 0 : (lo > t ? t : lo);
                    hi = wlo + WROWS_ - gbase; hi = hi < lo ? lo : (hi > t ? t : hi);
                } else { lo = t; hi = t; }

#define GSEG(KS, KE) do {                                                        \
    int k = (KS);                                                                \
    const v4f* pS = prow + (long)(gbase + k) * (D_ / 4);                         \
    for (; k + 4 <= (KE); k += 4) {                                              \
        v4f v0 = pS[lane], v1 = pS[lane+64], v2 = pS[lane+128], v3 = pS[lane+192];\
        acc0 += v0 * lane_bcast_f(Wl, k);   acc1 += v1 * lane_bcast_f(Wl, k+1);  \
        acc0 += v2 * lane_bcast_f(Wl, k+2); acc1 += v3 * lane_bcast_f(Wl, k+3);  \
        pS += 4 * (D_ / 4); }                                                    \
    for (; k < (KE); ++k) { v4f v = pS[lane]; acc0 += v * lane_bcast_f(Wl, k); pS += (D_ / 4); } \
} while (0)

                GSEG(0, lo);                               // prefix (usually empty)
                {                                          // LDS mid-segment
                    int k = lo;
                    const v4f* tp = tile + (gbase + lo - wlo) * 64 + lane;
                    for (; k + 4 <= hi; k += 4) {
                        v4f t0 = tp[0], t1 = tp[64], t2 = tp[128], t3 = tp[192];
                        acc0 += t0 * lane_bcast_f(Wl, k);   acc1 += t1 * lane_bcast_f(Wl, k+1);
                        acc0 += t2 * lane_bcast_f(Wl, k+2); acc1 += t3 * lane_bcast_f(Wl, k+3);
                        tp += 256;
                    }
                    for (; k < hi; ++k) { acc0 += tp[0] * lane_bcast_f(Wl, k); tp += 64; }
                }
                GSEG(hi, t);                               // suffix overhang
#undef GSEG
            }
        }

        const float inv_c = 1.0f / (float)(gh > 1 ? gh : 1);
        v4f res = (acc0 + acc1) * inv_c;
        v4f* op = (v4f*)out + ((long)n * P_ + p) * (D_ / 4) + lane;
        __builtin_nontemporal_store(res, op);
    }
}

extern "C" void kernel_launch(void* const* d_in, const int* in_sizes, int n_in,
                              void* d_out, int out_size, void* d_ws, size_t ws_size,
                              hipStream_t stream) {
    const float* feat      = (const float*)d_in[0];
    const float* boxes     = (const float*)d_in[1];
    const int*   batch_idx = (const int*)d_in[2];
    float*       out       = (float*)d_out;

    if (ws_size >= (size_t)(NBINS_ + NWIN_) * sizeof(int)) {
        int* binlist = (int*)d_ws;                       // 256 KB
        int* cnt     = binlist + NBINS_;                 // 2 KB
        hipMemsetAsync(cnt, 0, NWIN_ * sizeof(int), stream);
        count_bins_kernel<<<NBINS_ / 256, 256, 0, stream>>>(boxes, batch_idx, cnt);
        scan_kernel<<<1, NWIN_, 0, stream>>>(cnt);
        scatter_bins_kernel<<<NBINS_ / 256, 256, 0, stream>>>(boxes, batch_idx, cnt, binlist);
        roi_win_kernel<<<NBINS_ / CPB_, 512, 0, stream>>>(feat, boxes, batch_idx, binlist, out);
    } else {                                             // fallback: R5 path
        int* order = (int*)d_ws;                         // 8 KB
        build_order_kernel<<<1, 256, 0, stream>>>(batch_idx, order);
        roi_rows_kernel<<<(N_ * P_) / 4, 256, 0, stream>>>(feat, boxes, batch_idx, order, out);
    }
}